// Round 10
// baseline (342.380 us; speedup 1.0000x reference)
//
#include <hip/hip_runtime.h>
#include <hip/hip_fp16.h>

typedef _Float16 f16x8 __attribute__((ext_vector_type(8)));
typedef float f32x4 __attribute__((ext_vector_type(4)));

// ================= bucketed CSR build (r6-exact) =================
#define BSH 9
#define BSZ 512
#define CAP 12288

__global__ __launch_bounds__(256) void passA(const int* __restrict__ ei,
                                             int* __restrict__ bcount, int E, int NB) {
  __shared__ int hist[256];
  int t = threadIdx.x;
  hist[t] = 0;
  __syncthreads();
  for (int e = blockIdx.x * 256 + t; e < E; e += gridDim.x * 256)
    atomicAdd(&hist[ei[E + e] >> BSH], 1);
  __syncthreads();
  if (t < NB && hist[t]) atomicAdd(&bcount[t], hist[t]);
}

__global__ __launch_bounds__(256) void scanB(const int* __restrict__ bcount,
                                             int* __restrict__ bstart,
                                             int* __restrict__ bfill, int NB, int E) {
  __shared__ int s[256];
  int t = threadIdx.x;
  int v = (t < NB) ? bcount[t] : 0;
  s[t] = v;
  __syncthreads();
  for (int off = 1; off < 256; off <<= 1) {
    int add = (t >= off) ? s[t - off] : 0;
    __syncthreads();
    s[t] += add;
    __syncthreads();
  }
  if (t < NB) {
    int ex = s[t] - v;
    bstart[t] = ex;
    bfill[t] = ex;
  }
  if (t == 0) bstart[NB] = E;
}

// ============ MFMA GEMM body (r6-proven, row-major in/out) ============
template <int NC, int NWC, bool IN_F16, bool SCALE>
__device__ __forceinline__ void gemm_mfma_body(
    const void* __restrict__ Xv, const float* __restrict__ W,
    const float* __restrict__ dinv, _Float16* __restrict__ G, int nrows, int bid,
    _Float16* Bs) {
  int t = threadIdx.x;
  {
    int n = t % NC;
    int kh = (t / NC) * (NC / 2);
    constexpr int NBLK = (NC / 2) / 8;
#pragma unroll
    for (int b = 0; b < NBLK; ++b) {
      f16x8 tmp;
#pragma unroll
      for (int j = 0; j < 8; ++j)
        tmp[j] = (_Float16)W[(size_t)(kh + b * 8 + j) * NC + n];
      *(f16x8*)(&Bs[n * 136 + kh + b * 8]) = tmp;
    }
  }
  __syncthreads();

  int w = t >> 6, lane = t & 63;
  int m = lane & 15, q = lane >> 4;
  int wr = (w / NWC) * 64, wc = (w % NWC) * 64;
  int row0 = bid * ((4 / NWC) * 64);

  f32x4 acc[4][4];
#pragma unroll
  for (int rt = 0; rt < 4; ++rt)
#pragma unroll
    for (int ct = 0; ct < 4; ++ct)
#pragma unroll
      for (int qq = 0; qq < 4; ++qq) acc[rt][ct][qq] = 0.f;

#pragma unroll
  for (int kc = 0; kc < 4; ++kc) {
    int kbase = kc * 32 + q * 8;
    f16x8 af[4];
#pragma unroll
    for (int rt = 0; rt < 4; ++rt) {
      int row = row0 + wr + rt * 16 + m;
      if constexpr (IN_F16) {
        f16x8 a = {0, 0, 0, 0, 0, 0, 0, 0};
        if (row < nrows) a = *(const f16x8*)((const _Float16*)Xv + (size_t)row * 128 + kbase);
        af[rt] = a;
      } else {
        float4 x0 = {0, 0, 0, 0}, x1 = {0, 0, 0, 0};
        if (row < nrows) {
          const float* Xf = (const float*)Xv;
          x0 = *(const float4*)(Xf + (size_t)row * 128 + kbase);
          x1 = *(const float4*)(Xf + (size_t)row * 128 + kbase + 4);
        }
        f16x8 a;
        a[0] = (_Float16)x0.x; a[1] = (_Float16)x0.y;
        a[2] = (_Float16)x0.z; a[3] = (_Float16)x0.w;
        a[4] = (_Float16)x1.x; a[5] = (_Float16)x1.y;
        a[6] = (_Float16)x1.z; a[7] = (_Float16)x1.w;
        af[rt] = a;
      }
    }
    f16x8 bf[4];
#pragma unroll
    for (int ct = 0; ct < 4; ++ct) {
      int n = wc + ct * 16 + m;
      bf[ct] = *(f16x8*)(&Bs[n * 136 + kbase]);
    }
#pragma unroll
    for (int rt = 0; rt < 4; ++rt)
#pragma unroll
      for (int ct = 0; ct < 4; ++ct)
        acc[rt][ct] = __builtin_amdgcn_mfma_f32_16x16x32_f16(af[rt], bf[ct],
                                                             acc[rt][ct], 0, 0, 0);
  }
#pragma unroll
  for (int rt = 0; rt < 4; ++rt) {
#pragma unroll
    for (int r = 0; r < 4; ++r) {
      int row = row0 + wr + rt * 16 + q * 4 + r;
      if (row < nrows) {
        float d = SCALE ? dinv[row] : 1.f;
#pragma unroll
        for (int ct = 0; ct < 4; ++ct) {
          int col = wc + ct * 16 + m;
          G[(size_t)row * NC + col] = (_Float16)(acc[rt][ct][r] * d);
        }
      }
    }
  }
}

// ===== fused: gemm1 (MFMA, unscaled, fp32-in) interleaved with passB (r6-exact) =====
__global__ __launch_bounds__(256) void fused_gemm_passB(
    const float* __restrict__ X, const float* __restrict__ W1,
    _Float16* __restrict__ G, int nrows, int GB,
    const int* __restrict__ ei, int* __restrict__ bfill,
    unsigned int* __restrict__ pairs, int E, int PB) {
  __shared__ char smem[128 * 136 * 2];
  int g = blockIdx.x;
  int M2 = 2 * (GB < PB ? GB : PB);
  bool is_gemm;
  int bid;
  if (g < M2) { is_gemm = (g & 1) == 0; bid = g >> 1; }
  else        { is_gemm = (GB > PB);    bid = g - M2 + (GB < PB ? GB : PB); }
  if (is_gemm) {
    gemm_mfma_body<128, 2, false, false>(X, W1, nullptr, G, nrows, bid,
                                         (_Float16*)smem);
  } else {
    int* hist = (int*)smem;
    int* gbase = (int*)(smem + 1024);
    int t = threadIdx.x;
    hist[t] = 0;
    __syncthreads();
    int d[8], s[8], lp[8], bb[8];
    int base = bid * 2048;
#pragma unroll
    for (int u = 0; u < 8; ++u) {
      int e = base + u * 256 + t;
      if (e < E) {
        d[u] = ei[E + e];
        s[u] = ei[e];
        bb[u] = d[u] >> BSH;
        lp[u] = atomicAdd(&hist[bb[u]], 1);
      } else {
        bb[u] = -1;
      }
    }
    __syncthreads();
    if (hist[t]) gbase[t] = atomicAdd(&bfill[t], hist[t]);
    __syncthreads();
#pragma unroll
    for (int u = 0; u < 8; ++u)
      if (bb[u] >= 0)
        pairs[gbase[bb[u]] + lp[u]] =
            ((unsigned int)(d[u] & (BSZ - 1)) << 17) | (unsigned int)s[u];
  }
}

// passC: per-bucket LDS count/scan/fill (r6-exact)
__global__ __launch_bounds__(512) void passC(const unsigned int* __restrict__ pairs,
                                             const int* __restrict__ bstart,
                                             int* __restrict__ rowstart,
                                             int* __restrict__ deg,
                                             float* __restrict__ dinv,
                                             int* __restrict__ csr, int N) {
  __shared__ int hcnt[BSZ];
  __shared__ int lfill[BSZ];
  __shared__ int ss[512];
  __shared__ int lcsr[CAP];
  int b = blockIdx.x;
  int t = threadIdx.x;
  int lo = bstart[b], hi = bstart[b + 1];
  int cnt = hi - lo;
  int nbase = b << BSH;
  hcnt[t] = 0;
  __syncthreads();
  for (int k = lo + t; k < hi; k += 512)
    atomicAdd(&hcnt[(pairs[k] >> 17) & (BSZ - 1)], 1);
  __syncthreads();
  int v = hcnt[t];
  ss[t] = v;
  __syncthreads();
  for (int off = 1; off < 512; off <<= 1) {
    int add = (t >= off) ? ss[t - off] : 0;
    __syncthreads();
    ss[t] += add;
    __syncthreads();
  }
  int ex = ss[t] - v;
  lfill[t] = ex;
  int node = nbase + t;
  if (node < N) {
    rowstart[node] = lo + ex;
    deg[node] = v;
    dinv[node] = rsqrtf((float)(v + 1));
  }
  __syncthreads();
  bool fits = (cnt <= CAP);
  for (int k = lo + t; k < hi; k += 512) {
    unsigned int p = pairs[k];
    int pos = atomicAdd(&lfill[(p >> 17) & (BSZ - 1)], 1);
    int src = (int)(p & 0x1FFFFu);
    if (fits) lcsr[pos] = src;
    else      csr[lo + pos] = src;
  }
  __syncthreads();
  if (fits)
    for (int k = t; k < cnt; k += 512) csr[lo + k] = lcsr[k];
}

// ===== agg128_mm: layer-1 aggregation + layer-2 GEMM fused via MFMA =====
// Wave handles 16 nodes: per node (r6-proven loop)
//   h = relu(di*(di*G[i] + sum dinv[s]*G[s]) + b1)   -> LDS (fp16)
// then one 16x128 @ 128x64 MFMA batch: g2[i,:] = dinv[i] * (h @ W2).
// No barrier after initial W2 staging: Hs region is wave-private and
// wave-internal DS ordering guarantees the RAW.
#define HPAD 144   // halves per H row: 288 B, 16-B aligned, 4-way-conflict max
__global__ __launch_bounds__(256) void agg128_mm(
    const __half* __restrict__ G, const int* __restrict__ csr,
    const int* __restrict__ rowstart, const int* __restrict__ deg,
    const float* __restrict__ dinv, const float* __restrict__ b1,
    const float* __restrict__ W2, _Float16* __restrict__ g2, int N) {
  __shared__ _Float16 Ws[64 * 136];       // B layout: Ws[n*136+k] = W2[k][n]
  __shared__ _Float16 Hs[4][16 * HPAD];   // per-wave h rows
  int t = threadIdx.x;
  {
    int n = t & 63;
    int kh = (t >> 6) * 32;
#pragma unroll
    for (int b = 0; b < 4; ++b) {
      f16x8 tmp;
#pragma unroll
      for (int j = 0; j < 8; ++j)
        tmp[j] = (_Float16)W2[(size_t)(kh + b * 8 + j) * 64 + n];
      *(f16x8*)(&Ws[n * 136 + kh + b * 8]) = tmp;
    }
  }
  __syncthreads();

  int w = t >> 6, lane = t & 63;
  int m = lane & 15, q = lane >> 4;
  const __half2* Gp = (const __half2*)G;
  float2 bb = ((const float2*)b1)[lane];
  int node0 = (blockIdx.x * 4 + w) * 16;
  if (node0 >= N) return;   // wave-uniform; no barriers follow

  _Float16* H = Hs[w];
#pragma unroll 1
  for (int u = 0; u < 16; ++u) {
    int i = node0 + u;
    float2 h = {0.f, 0.f};
    if (i < N) {
      int ii = __builtin_amdgcn_readfirstlane(i);
      float di = dinv[ii];
      float2 g = __half22float2(Gp[(size_t)ii * 64 + lane]);
      float2 a = {di * g.x, di * g.y};
      int s = rowstart[ii];
      int d = deg[ii];
      int k = 0;
      for (; k + 3 < d; k += 4) {
        int s0 = csr[s + k], s1 = csr[s + k + 1];
        int s2 = csr[s + k + 2], s3 = csr[s + k + 3];
        float w0 = dinv[s0], w1 = dinv[s1], w2 = dinv[s2], w3 = dinv[s3];
        float2 v0 = __half22float2(Gp[(size_t)s0 * 64 + lane]);
        float2 v1 = __half22float2(Gp[(size_t)s1 * 64 + lane]);
        float2 v2 = __half22float2(Gp[(size_t)s2 * 64 + lane]);
        float2 v3 = __half22float2(Gp[(size_t)s3 * 64 + lane]);
        a.x = fmaf(w0, v0.x, a.x); a.y = fmaf(w0, v0.y, a.y);
        a.x = fmaf(w1, v1.x, a.x); a.y = fmaf(w1, v1.y, a.y);
        a.x = fmaf(w2, v2.x, a.x); a.y = fmaf(w2, v2.y, a.y);
        a.x = fmaf(w3, v3.x, a.x); a.y = fmaf(w3, v3.y, a.y);
      }
      for (; k < d; ++k) {
        int s0 = csr[s + k];
        float w0 = dinv[s0];
        float2 v0 = __half22float2(Gp[(size_t)s0 * 64 + lane]);
        a.x = fmaf(w0, v0.x, a.x); a.y = fmaf(w0, v0.y, a.y);
      }
      h.x = fmaxf(fmaf(di, a.x, bb.x), 0.f);
      h.y = fmaxf(fmaf(di, a.y, bb.y), 0.f);
    }
    H[u * HPAD + 2 * lane]     = (_Float16)h.x;
    H[u * HPAD + 2 * lane + 1] = (_Float16)h.y;
  }

  // MFMA: C[16 x 64] = H[16 x 128] @ W2[128 x 64]
  f32x4 acc[4];
#pragma unroll
  for (int ct = 0; ct < 4; ++ct)
#pragma unroll
    for (int qq = 0; qq < 4; ++qq) acc[ct][qq] = 0.f;
#pragma unroll
  for (int kc = 0; kc < 4; ++kc) {
    int kb = kc * 32 + q * 8;
    f16x8 af = *(f16x8*)(&H[m * HPAD + kb]);
#pragma unroll
    for (int ct = 0; ct < 4; ++ct) {
      f16x8 bf = *(f16x8*)(&Ws[(ct * 16 + m) * 136 + kb]);
      acc[ct] = __builtin_amdgcn_mfma_f32_16x16x32_f16(af, bf, acc[ct], 0, 0, 0);
    }
  }
  // C layout: row = q*4+r, col = ct*16+m; fold dinv[row] (g2 dinv-folded)
#pragma unroll
  for (int r = 0; r < 4; ++r) {
    int i = node0 + q * 4 + r;
    if (i < N) {
      float di = dinv[i];
#pragma unroll
      for (int ct = 0; ct < 4; ++ct)
        g2[(size_t)i * 64 + ct * 16 + m] = (_Float16)(acc[ct][r] * di);
    }
  }
}

// ===== agg64 v2 (r9-proven): half-wave per edge, 256 B per gather instr =====
__global__ __launch_bounds__(256) void agg64(
    const __half* __restrict__ G, const int* __restrict__ csr,
    const int* __restrict__ rowstart, const int* __restrict__ deg,
    const float* __restrict__ dinv, const float* __restrict__ bias,
    float* __restrict__ out, int n) {
  int wid = blockIdx.x * 4 + (threadIdx.x >> 6);
  if (wid >= n) return;
  int i = __builtin_amdgcn_readfirstlane(wid);
  int lane = threadIdx.x & 63;
  int e2 = lane >> 5, f = lane & 31;
  const __half2* Gp = (const __half2*)G;
  int r0 = rowstart[i];
  int d = deg[i];
  float2 acc = {0.f, 0.f};
  for (int k = 0; k < d; k += 4) {
    int kA = k + e2, kB = k + 2 + e2;
    int iA = i, iB = i;
    float wA = 0.f, wB = 0.f;
    if (kA < d) { iA = csr[r0 + kA]; wA = 1.f; }
    if (kB < d) { iB = csr[r0 + kB]; wB = 1.f; }
    float2 vA = __half22float2(Gp[(size_t)iA * 32 + f]);
    float2 vB = __half22float2(Gp[(size_t)iB * 32 + f]);
    acc.x = fmaf(wA, vA.x, acc.x); acc.y = fmaf(wA, vA.y, acc.y);
    acc.x = fmaf(wB, vB.x, acc.x); acc.y = fmaf(wB, vB.y, acc.y);
  }
  acc.x += __shfl_xor(acc.x, 32);
  acc.y += __shfl_xor(acc.y, 32);
  if (e2 == 0) {
    float di = dinv[i];
    float2 g = __half22float2(Gp[(size_t)i * 32 + f]);
    float2 b = ((const float2*)bias)[f];
    float2 o;
    o.x = fmaxf(fmaf(di, g.x + acc.x, b.x), 0.f);
    o.y = fmaxf(fmaf(di, g.y + acc.y, b.y), 0.f);
    ((float2*)out)[(size_t)i * 32 + f] = o;
  }
}

// ================= launch =================
extern "C" void kernel_launch(void* const* d_in, const int* in_sizes, int n_in,
                              void* d_out, int out_size, void* d_ws, size_t ws_size,
                              hipStream_t stream) {
  const float* x  = (const float*)d_in[0];
  const int*   ei = (const int*)d_in[1];
  const float* W1 = (const float*)d_in[2];
  const float* b1 = (const float*)d_in[3];
  const float* W2 = (const float*)d_in[4];
  const float* b2 = (const float*)d_in[5];
  float* out = (float*)d_out;

  const int N = in_sizes[0] / 128;
  const int E = in_sizes[1] / 2;
  const int NB = (N + BSZ - 1) >> BSH;   // 196 for N=100k

  char* base = (char*)d_ws;
  size_t off = 0;
  auto alloc = [&](size_t bytes) -> void* {
    void* p = base + off;
    off += (bytes + 255) & ~(size_t)255;
    return p;
  };
  int*          bcount   = (int*)alloc(256 * 4);
  int*          bstart   = (int*)alloc(260 * 4);
  int*          bfill    = (int*)alloc(256 * 4);
  int*          deg      = (int*)alloc((size_t)N * 4);
  int*          rowstart = (int*)alloc((size_t)N * 4);
  float*        dinv     = (float*)alloc((size_t)N * 4);
  int*          csr      = (int*)alloc((size_t)E * 4);
  unsigned int* pairs    = (unsigned int*)alloc((size_t)E * 4);
  __half*       g1       = (__half*)alloc((size_t)N * 128 * 2);
  __half*       g2       = (__half*)alloc((size_t)N * 64 * 2);

  hipMemsetAsync(bcount, 0, 256 * 4, stream);
  passA<<<512, 256, 0, stream>>>(ei, bcount, E, NB);
  scanB<<<1, 256, 0, stream>>>(bcount, bstart, bfill, NB, E);

  int GB = (N + 127) / 128;
  int PB = (E + 2047) / 2048;
  fused_gemm_passB<<<GB + PB, 256, 0, stream>>>(x, W1, (_Float16*)g1, N, GB, ei,
                                                bfill, pairs, E, PB);
  passC<<<NB, 512, 0, stream>>>(pairs, bstart, rowstart, deg, dinv, csr, N);

  int nmm = (N + 63) / 64;
  agg128_mm<<<nmm, 256, 0, stream>>>(g1, csr, rowstart, deg, dinv, b1, W2,
                                     (_Float16*)g2, N);
  int ng = (N + 3) / 4;
  agg64<<<ng, 256, 0, stream>>>(g2, csr, rowstart, deg, dinv, b2, out, N);
}

// Round 11
// 311.046 us; speedup vs baseline: 1.1007x; 1.1007x over previous
//
#include <hip/hip_runtime.h>
#include <hip/hip_fp16.h>

typedef _Float16 f16x8 __attribute__((ext_vector_type(8)));
typedef float f32x4 __attribute__((ext_vector_type(4)));

// ================= bucketed CSR build (r6-exact) =================
#define BSH 9
#define BSZ 512
#define CAP 12288

__global__ __launch_bounds__(256) void passA(const int* __restrict__ ei,
                                             int* __restrict__ bcount, int E, int NB) {
  __shared__ int hist[256];
  int t = threadIdx.x;
  hist[t] = 0;
  __syncthreads();
  for (int e = blockIdx.x * 256 + t; e < E; e += gridDim.x * 256)
    atomicAdd(&hist[ei[E + e] >> BSH], 1);
  __syncthreads();
  if (t < NB && hist[t]) atomicAdd(&bcount[t], hist[t]);
}

__global__ __launch_bounds__(256) void scanB(const int* __restrict__ bcount,
                                             int* __restrict__ bstart,
                                             int* __restrict__ bfill, int NB, int E) {
  __shared__ int s[256];
  int t = threadIdx.x;
  int v = (t < NB) ? bcount[t] : 0;
  s[t] = v;
  __syncthreads();
  for (int off = 1; off < 256; off <<= 1) {
    int add = (t >= off) ? s[t - off] : 0;
    __syncthreads();
    s[t] += add;
    __syncthreads();
  }
  if (t < NB) {
    int ex = s[t] - v;
    bstart[t] = ex;
    bfill[t] = ex;
  }
  if (t == 0) bstart[NB] = E;
}

// ============ MFMA GEMM body (r6-proven; used by gemm1) ============
template <int NC, int NWC, bool IN_F16, bool SCALE>
__device__ __forceinline__ void gemm_mfma_body(
    const void* __restrict__ Xv, const float* __restrict__ W,
    const float* __restrict__ dinv, _Float16* __restrict__ G, int nrows, int bid,
    _Float16* Bs) {
  int t = threadIdx.x;
  {
    int n = t % NC;
    int kh = (t / NC) * (NC / 2);
    constexpr int NBLK = (NC / 2) / 8;
#pragma unroll
    for (int b = 0; b < NBLK; ++b) {
      f16x8 tmp;
#pragma unroll
      for (int j = 0; j < 8; ++j)
        tmp[j] = (_Float16)W[(size_t)(kh + b * 8 + j) * NC + n];
      *(f16x8*)(&Bs[n * 136 + kh + b * 8]) = tmp;
    }
  }
  __syncthreads();

  int w = t >> 6, lane = t & 63;
  int m = lane & 15, q = lane >> 4;
  int wr = (w / NWC) * 64, wc = (w % NWC) * 64;
  int row0 = bid * ((4 / NWC) * 64);

  f32x4 acc[4][4];
#pragma unroll
  for (int rt = 0; rt < 4; ++rt)
#pragma unroll
    for (int ct = 0; ct < 4; ++ct)
#pragma unroll
      for (int qq = 0; qq < 4; ++qq) acc[rt][ct][qq] = 0.f;

#pragma unroll
  for (int kc = 0; kc < 4; ++kc) {
    int kbase = kc * 32 + q * 8;
    f16x8 af[4];
#pragma unroll
    for (int rt = 0; rt < 4; ++rt) {
      int row = row0 + wr + rt * 16 + m;
      if constexpr (IN_F16) {
        f16x8 a = {0, 0, 0, 0, 0, 0, 0, 0};
        if (row < nrows) a = *(const f16x8*)((const _Float16*)Xv + (size_t)row * 128 + kbase);
        af[rt] = a;
      } else {
        float4 x0 = {0, 0, 0, 0}, x1 = {0, 0, 0, 0};
        if (row < nrows) {
          const float* Xf = (const float*)Xv;
          x0 = *(const float4*)(Xf + (size_t)row * 128 + kbase);
          x1 = *(const float4*)(Xf + (size_t)row * 128 + kbase + 4);
        }
        f16x8 a;
        a[0] = (_Float16)x0.x; a[1] = (_Float16)x0.y;
        a[2] = (_Float16)x0.z; a[3] = (_Float16)x0.w;
        a[4] = (_Float16)x1.x; a[5] = (_Float16)x1.y;
        a[6] = (_Float16)x1.z; a[7] = (_Float16)x1.w;
        af[rt] = a;
      }
    }
    f16x8 bf[4];
#pragma unroll
    for (int ct = 0; ct < 4; ++ct) {
      int n = wc + ct * 16 + m;
      bf[ct] = *(f16x8*)(&Bs[n * 136 + kbase]);
    }
#pragma unroll
    for (int rt = 0; rt < 4; ++rt)
#pragma unroll
      for (int ct = 0; ct < 4; ++ct)
        acc[rt][ct] = __builtin_amdgcn_mfma_f32_16x16x32_f16(af[rt], bf[ct],
                                                             acc[rt][ct], 0, 0, 0);
  }
#pragma unroll
  for (int rt = 0; rt < 4; ++rt) {
#pragma unroll
    for (int r = 0; r < 4; ++r) {
      int row = row0 + wr + rt * 16 + q * 4 + r;
      if (row < nrows) {
        float d = SCALE ? dinv[row] : 1.f;
#pragma unroll
        for (int ct = 0; ct < 4; ++ct) {
          int col = wc + ct * 16 + m;
          G[(size_t)row * NC + col] = (_Float16)(acc[rt][ct][r] * d);
        }
      }
    }
  }
}

// ===== fused: gemm1 (MFMA, unscaled, fp32-in) interleaved with passB (r6-exact) =====
__global__ __launch_bounds__(256) void fused_gemm_passB(
    const float* __restrict__ X, const float* __restrict__ W1,
    _Float16* __restrict__ G, int nrows, int GB,
    const int* __restrict__ ei, int* __restrict__ bfill,
    unsigned int* __restrict__ pairs, int E, int PB) {
  __shared__ char smem[128 * 136 * 2];
  int g = blockIdx.x;
  int M2 = 2 * (GB < PB ? GB : PB);
  bool is_gemm;
  int bid;
  if (g < M2) { is_gemm = (g & 1) == 0; bid = g >> 1; }
  else        { is_gemm = (GB > PB);    bid = g - M2 + (GB < PB ? GB : PB); }
  if (is_gemm) {
    gemm_mfma_body<128, 2, false, false>(X, W1, nullptr, G, nrows, bid,
                                         (_Float16*)smem);
  } else {
    int* hist = (int*)smem;
    int* gbase = (int*)(smem + 1024);
    int t = threadIdx.x;
    hist[t] = 0;
    __syncthreads();
    int d[8], s[8], lp[8], bb[8];
    int base = bid * 2048;
#pragma unroll
    for (int u = 0; u < 8; ++u) {
      int e = base + u * 256 + t;
      if (e < E) {
        d[u] = ei[E + e];
        s[u] = ei[e];
        bb[u] = d[u] >> BSH;
        lp[u] = atomicAdd(&hist[bb[u]], 1);
      } else {
        bb[u] = -1;
      }
    }
    __syncthreads();
    if (hist[t]) gbase[t] = atomicAdd(&bfill[t], hist[t]);
    __syncthreads();
#pragma unroll
    for (int u = 0; u < 8; ++u)
      if (bb[u] >= 0)
        pairs[gbase[bb[u]] + lp[u]] =
            ((unsigned int)(d[u] & (BSZ - 1)) << 17) | (unsigned int)s[u];
  }
}

// passC: per-bucket LDS count/scan/fill (r6-exact)
__global__ __launch_bounds__(512) void passC(const unsigned int* __restrict__ pairs,
                                             const int* __restrict__ bstart,
                                             int* __restrict__ rowstart,
                                             int* __restrict__ deg,
                                             float* __restrict__ dinv,
                                             int* __restrict__ csr, int N) {
  __shared__ int hcnt[BSZ];
  __shared__ int lfill[BSZ];
  __shared__ int ss[512];
  __shared__ int lcsr[CAP];
  int b = blockIdx.x;
  int t = threadIdx.x;
  int lo = bstart[b], hi = bstart[b + 1];
  int cnt = hi - lo;
  int nbase = b << BSH;
  hcnt[t] = 0;
  __syncthreads();
  for (int k = lo + t; k < hi; k += 512)
    atomicAdd(&hcnt[(pairs[k] >> 17) & (BSZ - 1)], 1);
  __syncthreads();
  int v = hcnt[t];
  ss[t] = v;
  __syncthreads();
  for (int off = 1; off < 512; off <<= 1) {
    int add = (t >= off) ? ss[t - off] : 0;
    __syncthreads();
    ss[t] += add;
    __syncthreads();
  }
  int ex = ss[t] - v;
  lfill[t] = ex;
  int node = nbase + t;
  if (node < N) {
    rowstart[node] = lo + ex;
    deg[node] = v;
    dinv[node] = rsqrtf((float)(v + 1));
  }
  __syncthreads();
  bool fits = (cnt <= CAP);
  for (int k = lo + t; k < hi; k += 512) {
    unsigned int p = pairs[k];
    int pos = atomicAdd(&lfill[(p >> 17) & (BSZ - 1)], 1);
    int src = (int)(p & 0x1FFFFu);
    if (fits) lcsr[pos] = src;
    else      csr[lo + pos] = src;
  }
  __syncthreads();
  if (fits)
    for (int k = t; k < cnt; k += 512) csr[lo + k] = lcsr[k];
}

// ===== gemm2s: x2 @ W2 (dinv-folded) with 32-row wave tiles =====
// 782 blocks x 4 waves (vs 391 in r6) -> 2x latency hiding on A-loads.
__global__ __launch_bounds__(256) void gemm2s(const _Float16* __restrict__ X,
                                              const float* __restrict__ W,
                                              const float* __restrict__ dinv,
                                              _Float16* __restrict__ G, int nrows) {
  __shared__ _Float16 Bs[64 * 136];
  int t = threadIdx.x;
  {
    int n = t & 63;
    int kh = (t >> 6) * 32;
#pragma unroll
    for (int b = 0; b < 4; ++b) {
      f16x8 tmp;
#pragma unroll
      for (int j = 0; j < 8; ++j)
        tmp[j] = (_Float16)W[(size_t)(kh + b * 8 + j) * 64 + n];
      *(f16x8*)(&Bs[n * 136 + kh + b * 8]) = tmp;
    }
  }
  __syncthreads();

  int w = t >> 6, lane = t & 63;
  int m = lane & 15, q = lane >> 4;
  int row0 = blockIdx.x * 128 + w * 32;

  f32x4 acc[2][4];
#pragma unroll
  for (int rt = 0; rt < 2; ++rt)
#pragma unroll
    for (int ct = 0; ct < 4; ++ct)
#pragma unroll
      for (int qq = 0; qq < 4; ++qq) acc[rt][ct][qq] = 0.f;

#pragma unroll
  for (int kc = 0; kc < 4; ++kc) {
    int kb = kc * 32 + q * 8;
    f16x8 af[2];
#pragma unroll
    for (int rt = 0; rt < 2; ++rt) {
      int row = row0 + rt * 16 + m;
      f16x8 a = {0, 0, 0, 0, 0, 0, 0, 0};
      if (row < nrows) a = *(const f16x8*)(X + (size_t)row * 128 + kb);
      af[rt] = a;
    }
#pragma unroll
    for (int ct = 0; ct < 4; ++ct) {
      f16x8 bf = *(f16x8*)(&Bs[(ct * 16 + m) * 136 + kb]);
#pragma unroll
      for (int rt = 0; rt < 2; ++rt)
        acc[rt][ct] = __builtin_amdgcn_mfma_f32_16x16x32_f16(af[rt], bf,
                                                             acc[rt][ct], 0, 0, 0);
    }
  }
#pragma unroll
  for (int rt = 0; rt < 2; ++rt) {
#pragma unroll
    for (int r = 0; r < 4; ++r) {
      int row = row0 + rt * 16 + q * 4 + r;
      if (row < nrows) {
        float d = dinv[row];
#pragma unroll
        for (int ct = 0; ct < 4; ++ct)
          G[(size_t)row * 64 + ct * 16 + m] = (_Float16)(acc[rt][ct][r] * d);
      }
    }
  }
}

// ===== agg128 (r6-exact): x2[i]=relu(di*(di*G[i]+sum dinv[s]*G[s])+b1) =====
__global__ __launch_bounds__(256) void agg128(
    const __half* __restrict__ G, const int* __restrict__ csr,
    const int* __restrict__ rowstart, const int* __restrict__ deg,
    const float* __restrict__ dinv, const float* __restrict__ bias,
    __half* __restrict__ out, int n) {
  int wid = blockIdx.x * 4 + (threadIdx.x >> 6);
  if (wid >= n) return;
  int i = __builtin_amdgcn_readfirstlane(wid);
  int lane = threadIdx.x & 63;
  const __half2* Gp = (const __half2*)G;
  float di = dinv[i];
  float2 g = __half22float2(Gp[(size_t)i * 64 + lane]);
  float2 a = {di * g.x, di * g.y};
  int s = rowstart[i];
  int d = deg[i];
  int k = 0;
  for (; k + 3 < d; k += 4) {
    int s0 = csr[s + k], s1 = csr[s + k + 1];
    int s2 = csr[s + k + 2], s3 = csr[s + k + 3];
    float w0 = dinv[s0], w1 = dinv[s1], w2 = dinv[s2], w3 = dinv[s3];
    float2 v0 = __half22float2(Gp[(size_t)s0 * 64 + lane]);
    float2 v1 = __half22float2(Gp[(size_t)s1 * 64 + lane]);
    float2 v2 = __half22float2(Gp[(size_t)s2 * 64 + lane]);
    float2 v3 = __half22float2(Gp[(size_t)s3 * 64 + lane]);
    a.x = fmaf(w0, v0.x, a.x); a.y = fmaf(w0, v0.y, a.y);
    a.x = fmaf(w1, v1.x, a.x); a.y = fmaf(w1, v1.y, a.y);
    a.x = fmaf(w2, v2.x, a.x); a.y = fmaf(w2, v2.y, a.y);
    a.x = fmaf(w3, v3.x, a.x); a.y = fmaf(w3, v3.y, a.y);
  }
  for (; k < d; ++k) {
    int s0 = csr[s + k];
    float w0 = dinv[s0];
    float2 v0 = __half22float2(Gp[(size_t)s0 * 64 + lane]);
    a.x = fmaf(w0, v0.x, a.x); a.y = fmaf(w0, v0.y, a.y);
  }
  float2 b = ((const float2*)bias)[lane];
  float ox = fmaxf(fmaf(di, a.x, b.x), 0.f);
  float oy = fmaxf(fmaf(di, a.y, b.y), 0.f);
  ((__half2*)out)[(size_t)i * 64 + lane] = __floats2half2_rn(ox, oy);
}

// ===== agg64 v2: half-wave per edge, 2 rows (256 B) per gather instr =====
__global__ __launch_bounds__(256) void agg64(
    const __half* __restrict__ G, const int* __restrict__ csr,
    const int* __restrict__ rowstart, const int* __restrict__ deg,
    const float* __restrict__ dinv, const float* __restrict__ bias,
    float* __restrict__ out, int n) {
  int wid = blockIdx.x * 4 + (threadIdx.x >> 6);
  if (wid >= n) return;
  int i = __builtin_amdgcn_readfirstlane(wid);
  int lane = threadIdx.x & 63;
  int e2 = lane >> 5, f = lane & 31;
  const __half2* Gp = (const __half2*)G;
  int r0 = rowstart[i];
  int d = deg[i];
  float2 acc = {0.f, 0.f};
  for (int k = 0; k < d; k += 4) {
    int kA = k + e2, kB = k + 2 + e2;
    int iA = i, iB = i;
    float wA = 0.f, wB = 0.f;
    if (kA < d) { iA = csr[r0 + kA]; wA = 1.f; }
    if (kB < d) { iB = csr[r0 + kB]; wB = 1.f; }
    float2 vA = __half22float2(Gp[(size_t)iA * 32 + f]);
    float2 vB = __half22float2(Gp[(size_t)iB * 32 + f]);
    acc.x = fmaf(wA, vA.x, acc.x); acc.y = fmaf(wA, vA.y, acc.y);
    acc.x = fmaf(wB, vB.x, acc.x); acc.y = fmaf(wB, vB.y, acc.y);
  }
  acc.x += __shfl_xor(acc.x, 32);
  acc.y += __shfl_xor(acc.y, 32);
  if (e2 == 0) {
    float di = dinv[i];
    float2 g = __half22float2(Gp[(size_t)i * 32 + f]);
    float2 b = ((const float2*)bias)[f];
    float2 o;
    o.x = fmaxf(fmaf(di, g.x + acc.x, b.x), 0.f);
    o.y = fmaxf(fmaf(di, g.y + acc.y, b.y), 0.f);
    ((float2*)out)[(size_t)i * 32 + f] = o;
  }
}

// ================= launch =================
extern "C" void kernel_launch(void* const* d_in, const int* in_sizes, int n_in,
                              void* d_out, int out_size, void* d_ws, size_t ws_size,
                              hipStream_t stream) {
  const float* x  = (const float*)d_in[0];
  const int*   ei = (const int*)d_in[1];
  const float* W1 = (const float*)d_in[2];
  const float* b1 = (const float*)d_in[3];
  const float* W2 = (const float*)d_in[4];
  const float* b2 = (const float*)d_in[5];
  float* out = (float*)d_out;

  const int N = in_sizes[0] / 128;
  const int E = in_sizes[1] / 2;
  const int NB = (N + BSZ - 1) >> BSH;   // 196 for N=100k

  char* base = (char*)d_ws;
  size_t off = 0;
  auto alloc = [&](size_t bytes) -> void* {
    void* p = base + off;
    off += (bytes + 255) & ~(size_t)255;
    return p;
  };
  int*          bcount   = (int*)alloc(256 * 4);
  int*          bstart   = (int*)alloc(260 * 4);
  int*          bfill    = (int*)alloc(256 * 4);
  int*          deg      = (int*)alloc((size_t)N * 4);
  int*          rowstart = (int*)alloc((size_t)N * 4);
  float*        dinv     = (float*)alloc((size_t)N * 4);
  int*          csr      = (int*)alloc((size_t)E * 4);
  unsigned int* pairs    = (unsigned int*)alloc((size_t)E * 4);
  __half*       g1       = (__half*)alloc((size_t)N * 128 * 2);
  __half*       x2       = (__half*)alloc((size_t)N * 128 * 2);
  __half*       g2       = (__half*)alloc((size_t)N * 64 * 2);

  hipMemsetAsync(bcount, 0, 256 * 4, stream);
  passA<<<512, 256, 0, stream>>>(ei, bcount, E, NB);
  scanB<<<1, 256, 0, stream>>>(bcount, bstart, bfill, NB, E);

  int GB = (N + 127) / 128;
  int PB = (E + 2047) / 2048;
  fused_gemm_passB<<<GB + PB, 256, 0, stream>>>(x, W1, (_Float16*)g1, N, GB, ei,
                                                bfill, pairs, E, PB);
  passC<<<NB, 512, 0, stream>>>(pairs, bstart, rowstart, deg, dinv, csr, N);

  int ng = (N + 3) / 4;
  agg128<<<ng, 256, 0, stream>>>(g1, csr, rowstart, deg, dinv, b1, x2, N);
  int G2B = (N + 127) / 128;
  gemm2s<<<G2B, 256, 0, stream>>>((const _Float16*)x2, W2, dinv,
                                  (_Float16*)g2, N);
  agg64<<<ng, 256, 0, stream>>>(g2, csr, rowstart, deg, dinv, b2, out, N);
}